// Round 6
// baseline (67.553 us; speedup 1.0000x reference)
//
#include <hip/hip_runtime.h>
#include <hip/hip_bf16.h>
#include <stdint.h>

typedef __attribute__((ext_vector_type(8)))  __bf16   bf16x8;
typedef __attribute__((ext_vector_type(16))) float    f32x16;
typedef __attribute__((ext_vector_type(8)))  float    f32x8;

#define NB   32
#define NN   2000
#define NK   32
#define NF   64
#define NOUT 128
#define NSTEP 130   // packed K: 2048 x-part + 32 dist, /16

#define GLOBAL_AS __attribute__((address_space(1)))
#define LDS_AS    __attribute__((address_space(3)))
#define SB() __builtin_amdgcn_sched_barrier(0)

// ---------------------------------------------------------------------------
// Fused prep. Blocks [0,NN): x -> xb2 frag-order tiles via LDS transpose
//   (coalesced read AND write) + dist -> db bf16.
// Blocks [NN, NN+NSTEP): W -> Wf B-fragment order.
// xb2 tile byte t*16 holds x[batch=col][f=s*16+half*8+j], t=s*64+half*32+col.
// Wf byte layout: kstep*4096 + wv*1024 + lane*16, o = wv*32 + (lane&31),
//                 k = kstep*16 + (lane>>5)*8 + j.
// ---------------------------------------------------------------------------
__global__ void kprep(const float* __restrict__ x, const float* __restrict__ dist,
                      const float* __restrict__ W,
                      __bf16* __restrict__ xb2, __bf16* __restrict__ db,
                      __bf16* __restrict__ Wf) {
  const int t = threadIdx.x;
  if (blockIdx.x < NN) {
    __shared__ __bf16 sm[32 * 66];            // 66-elem rows: conflict-free both phases
    const int n = blockIdx.x;
    const int bb = t >> 3;                    // batch row 0..31
    const int f0 = (t & 7) << 3;              // feature 0..56
    const float* src = x + ((size_t)bb * NN + n) * NF + f0;
    f32x8 v = *(const f32x8*)src;             // 256B/8-thread coalesced
    bf16x8 r;
#pragma unroll
    for (int j = 0; j < 8; ++j) r[j] = (__bf16)v[j];
    *(bf16x8*)&sm[bb * 66 + f0] = r;
    __syncthreads();
    const int col = t & 31, half = (t >> 5) & 1, s = t >> 6;
    bf16x8 o = *(const bf16x8*)&sm[col * 66 + s * 16 + half * 8];
    *(bf16x8*)((char*)xb2 + ((size_t)n << 12) + t * 16) = o;   // linear 4KB store
    if (t < NK) db[n * NK + t] = (__bf16)dist[n * NK + t];
  } else {
    const int kstep = blockIdx.x - NN;        // 0..129
    const int lane = t & 63;
    const int wv = t >> 6;
    const int o = wv * 32 + (lane & 31);
    const int kbase = kstep * 16 + (lane >> 5) * 8;
    bf16x8 r;
#pragma unroll
    for (int j = 0; j < 8; ++j) {
      const int kg = kbase + j;
      const int c = (kg < 2048) ? ((kg >> 6) * 65 + (kg & 63)) : ((kg - 2048) * 65 + 64);
      r[j] = (__bf16)W[(size_t)o * 2080 + c];
    }
    *(bf16x8*)(Wf + (((size_t)kstep * 256 + t) << 3)) = r;
  }
}

// ---------------------------------------------------------------------------
// Main: block = 2 seq positions, 4 waves: wave w = (n' = w>>1) x (og-pair = w&1).
// Each wave: A-frag read once, reused for 2 MFMAs (2 out-groups) -> block-chunk
// LDS reads 16 (was 64). Grid 1000 -> ~4 waves/SIMD. Depth-4 LDS (32KB),
// stage post-barrier (WAR-safe), steady vmcnt(10).
// ---------------------------------------------------------------------------
__global__ __launch_bounds__(256, 4) void kmain(
    const int* __restrict__ nbrs, const float* __restrict__ bias,
    const __bf16* __restrict__ xb2, const __bf16* __restrict__ Wf,
    const __bf16* __restrict__ db, float* __restrict__ out) {
  __shared__ __align__(16) char lds[4][2][4096];   // [buf][n'][frag-order tile]

  const int n0   = blockIdx.x * 2;
  const int t    = threadIdx.x;
  const int lane = t & 63;
  const int w    = t >> 6;
  const int col  = lane & 31;
  const int half = lane >> 5;
  const int np   = w >> 1;        // my n' (compute AND stage tile)
  const int ogp  = w & 1;         // my out-group pair (og = ogp*2, ogp*2+1)

  f32x16 acc0 = {}, acc1 = {};

  int myidx = 0;
  if (lane < NK) myidx = nbrs[(n0 + np) * NK + lane];

  // B-frag base: byte = kstep*4096 + (2*ogp)*1024 + lane*16; partner wv at +1024
  const char* wfb = (const char*)Wf + (ogp << 11) + lane * 16;

  auto stage = [&](int buf, int c) {     // wave stages its half (ogp) of tile np
    const int nb = __builtin_amdgcn_readlane(myidx, c);
    const char* g = (const char*)xb2 + ((size_t)nb << 12) + (ogp << 11) + lane * 16;
    char* l = &lds[buf][np][0] + (ogp << 11);
#pragma unroll
    for (int q = 0; q < 2; ++q)
      __builtin_amdgcn_global_load_lds(
          (const GLOBAL_AS uint32_t*)(g + (q << 10)),
          (LDS_AS uint32_t*)(l + (q << 10)), 16, 0, 0);
  };

  auto loadB = [&](bf16x8* B, int i) {   // 8 frags: 4 ksteps x 2 og
#pragma unroll
    for (int s = 0; s < 4; ++s) {
      B[s * 2 + 0] = *(const bf16x8*)(wfb + ((size_t)(i * 4 + s) << 12));
      B[s * 2 + 1] = *(const bf16x8*)(wfb + ((size_t)(i * 4 + s) << 12) + 1024);
    }
  };

  auto compute = [&](int buf, const bf16x8* B) {
    __builtin_amdgcn_s_setprio(1);
#pragma unroll
    for (int s = 0; s < 4; ++s) {
      bf16x8 a = *(const bf16x8*)(&lds[buf][np][0] + (s << 10) + lane * 16);
      acc0 = __builtin_amdgcn_mfma_f32_32x32x16_bf16(a, B[s * 2 + 0], acc0, 0, 0, 0);
      acc1 = __builtin_amdgcn_mfma_f32_32x32x16_bf16(a, B[s * 2 + 1], acc1, 0, 0, 0);
    }
    __builtin_amdgcn_s_setprio(0);
  };

  bf16x8 BA[8], BB[8];

  // prologue: S0,S1,L0 | barrier | S2  (matches steady queue shape)
  stage(0, 0); SB();
  stage(1, 1); SB();
  loadB(BA, 0); SB();
  __builtin_amdgcn_s_barrier();
  stage(2, 2); SB();

  // steady: chunks 0..27; per chunk: L(j+1) | vmcnt(10) | barrier | S(j+3) | compute(j)
  for (int j = 0; j < 28; j += 2) {
    loadB(BB, j + 1); SB();
    asm volatile("s_waitcnt vmcnt(10)" ::: "memory");
    __builtin_amdgcn_s_barrier(); SB();
    stage((j + 3) & 3, j + 3); SB();
    compute(j & 3, BA);

    loadB(BA, j + 2); SB();
    asm volatile("s_waitcnt vmcnt(10)" ::: "memory");
    __builtin_amdgcn_s_barrier(); SB();
    stage((j + 4) & 3, j + 4); SB();
    compute((j + 1) & 3, BB);
  }
  // chunk 28 (stages S31)
  loadB(BB, 29); SB();
  asm volatile("s_waitcnt vmcnt(10)" ::: "memory");
  __builtin_amdgcn_s_barrier(); SB();
  stage(31 & 3, 31); SB();
  compute(28 & 3, BA);
  // chunk 29
  loadB(BA, 30); SB();
  asm volatile("s_waitcnt vmcnt(10)" ::: "memory");
  __builtin_amdgcn_s_barrier(); SB();
  compute(29 & 3, BB);
  // chunk 30
  loadB(BB, 31); SB();
  asm volatile("s_waitcnt vmcnt(8)" ::: "memory");
  __builtin_amdgcn_s_barrier(); SB();
  compute(30 & 3, BA);
  // chunk 31
  asm volatile("s_waitcnt vmcnt(0)" ::: "memory");
  __builtin_amdgcn_s_barrier(); SB();
  compute(31 & 3, BB);

  // ---- distance ksteps 128,129 (A rows all equal d[n][k-slice])
#pragma unroll
  for (int s = 0; s < 2; ++s) {
    bf16x8 dv = *(const bf16x8*)((const char*)db + (size_t)(n0 + np) * 64 + s * 32 + half * 16);
    bf16x8 b0 = *(const bf16x8*)(wfb + ((size_t)(128 + s) << 12));
    bf16x8 b1 = *(const bf16x8*)(wfb + ((size_t)(128 + s) << 12) + 1024);
    acc0 = __builtin_amdgcn_mfma_f32_32x32x16_bf16(dv, b0, acc0, 0, 0, 0);
    acc1 = __builtin_amdgcn_mfma_f32_32x32x16_bf16(dv, b1, acc1, 0, 0, 0);
  }

  // ---- epilogue: D col=lane&31 -> out col, row=(r&3)+8*(r>>2)+4*half -> batch
  const int o0 = ogp * 64 + col;
  const int nn = n0 + np;
  const float bv0 = bias[o0], bv1 = bias[o0 + 32];
#pragma unroll
  for (int r = 0; r < 16; ++r) {
    const int row = (r & 3) + 8 * (r >> 2) + 4 * half;
    float* op = out + ((size_t)row * NN + nn) * NOUT + o0;
    op[0]  = acc0[r] + bv0;
    op[32] = acc1[r] + bv1;
  }
}

// ---------------------------------------------------------------------------
extern "C" void kernel_launch(void* const* d_in, const int* in_sizes, int n_in,
                              void* d_out, int out_size, void* d_ws, size_t ws_size,
                              hipStream_t stream) {
  const float* x    = (const float*)d_in[0];
  const int*   nbrs = (const int*)d_in[1];
  const float* dist = (const float*)d_in[2];
  const float* W    = (const float*)d_in[3];
  const float* bias = (const float*)d_in[4];
  float* out = (float*)d_out;

  char* ws = (char*)d_ws;
  __bf16* xb2 = (__bf16*)(ws);                          // 2000*4096  = 8,192,000 B
  __bf16* Wf  = (__bf16*)(ws + 8192000);                // 130*256*16 =   532,480 B
  __bf16* db  = (__bf16*)(ws + 8192000 + 532480);       // 2000*32*2  =   128,000 B

  kprep<<<NN + NSTEP, 256, 0, stream>>>(x, dist, W, xb2, db, Wf);
  kmain<<<NN / 2, 256, 0, stream>>>(nbrs, bias, xb2, Wf, db, out);
}